// Round 1
// baseline (80.407 us; speedup 1.0000x reference)
//
#include <hip/hip_runtime.h>
#include <math.h>

#define LOG2E 1.4426950408889634f
#define LN2   0.6931471805599453f

static constexpr int M = 1024;
static constexpr int N = 65536;

// ws layout: float coef[M*8] (c0..c5, pad, pad per component, log2e-scaled), then float L2 = log2e * max_j log_w_j
// needed ws bytes = (M*8 + 1) * 4 = 32772

__global__ __launch_bounds__(1024)
void gm_prep(const float* __restrict__ mu,
             const float* __restrict__ A,
             const float* __restrict__ w,
             float* __restrict__ ws) {
    __shared__ float red[1024];
    const int j = threadIdx.x;

    // gamma = A A^T (symmetric 2x2)
    const float4 a = ((const float4*)A)[j];          // a00,a01,a10,a11
    const float g00 = a.x*a.x + a.y*a.y;
    const float g01 = a.x*a.z + a.y*a.w;
    const float g11 = a.z*a.z + a.w*a.w;
    const float2 m  = ((const float2*)mu)[j];
    const float gm0 = g00*m.x + g01*m.y;
    const float gm1 = g01*m.x + g11*m.y;
    const float mGm = gm0*m.x + gm1*m.y;
    const float det = g00*g11 - g01*g01;
    const float wj  = w[j];

    // logsumexp over w: max
    red[j] = wj; __syncthreads();
    for (int off = 512; off > 0; off >>= 1) {
        if (j < off) red[j] = fmaxf(red[j], red[j+off]);
        __syncthreads();
    }
    const float wmax = red[0]; __syncthreads();
    red[j] = expf(wj - wmax); __syncthreads();
    for (int off = 512; off > 0; off >>= 1) {
        if (j < off) red[j] = red[j] + red[j+off];
        __syncthreads();
    }
    const float lse = wmax + logf(red[0]); __syncthreads();

    const float log_w = wj - lse + 0.5f * logf(det);

    // L = max_j log_w_j  (global shift; v = log_w - q <= L since q >= 0)
    red[j] = log_w; __syncthreads();
    for (int off = 512; off > 0; off >>= 1) {
        if (j < off) red[j] = fmaxf(red[j], red[j+off]);
        __syncthreads();
    }
    const float L = red[0];

    float* c = ws + j*8;
    c[0] = LOG2E * (log_w - mGm - L);
    c[1] = LOG2E * 2.0f * gm0;
    c[2] = LOG2E * 2.0f * gm1;
    c[3] = -LOG2E * g00;
    c[4] = -LOG2E * 2.0f * g01;
    c[5] = -LOG2E * g11;
    c[6] = 0.0f;
    c[7] = 0.0f;
    if (j == 0) ws[M*8] = LOG2E * L;
}

// 1024 blocks x 256 threads. Each block handles 64 samples; the 4 waves of a
// block each take a 256-component chunk of M (4-way split-M for occupancy).
__global__ __launch_bounds__(256)
void gm_main(const float* __restrict__ sample,
             const float* __restrict__ ws,
             float* __restrict__ out) {
    __shared__ __align__(16) float coef[M*8];   // 32 KiB
    __shared__ float partial[256];
    __shared__ float sL2;
    const int t = threadIdx.x;

    // stage coefficients global -> LDS (coalesced float4)
    const float4* wsv = (const float4*)ws;
    float4* cv = (float4*)coef;
    #pragma unroll
    for (int k = 0; k < 8; k++)
        cv[t + 256*k] = wsv[t + 256*k];
    if (t == 0) sL2 = ws[M*8];
    __syncthreads();

    const int lane  = t & 63;
    const int chunk = t >> 6;                    // 0..3
    const int i = blockIdx.x*64 + lane;

    const float2 xy = ((const float2*)sample)[i];
    const float x0 = xy.x, x1 = xy.y;
    const float xx = x0*x0, xyp = x0*x1, yy = x1*x1;

    float s0 = 0.0f, s1 = 0.0f;
    const float* c = coef + chunk*256*8;
    #pragma unroll 8
    for (int jj = 0; jj < 256; jj++) {
        const float* cc = c + jj*8;
        // 5-FMA chain; all lanes read same LDS address -> broadcast, no conflicts
        const float v = fmaf(cc[5], yy,
                        fmaf(cc[4], xyp,
                        fmaf(cc[3], xx,
                        fmaf(cc[2], x1,
                        fmaf(cc[1], x0, cc[0])))));
        const float e = __builtin_amdgcn_exp2f(v);
        if (jj & 1) s1 += e; else s0 += e;
    }
    partial[t] = s0 + s1;
    __syncthreads();

    if (t < 64) {
        const float s = partial[t] + partial[t+64] + partial[t+128] + partial[t+192];
        out[blockIdx.x*64 + t] = LN2 * (sL2 + __builtin_amdgcn_logf(s));
    }
}

// Fallback if ws is too small: fused per-block prep (redundant across the
// 256 blocks, but self-contained). 256 blocks x 256 threads, 1 sample/thread.
__global__ __launch_bounds__(256)
void gm_fused(const float* __restrict__ sample,
              const float* __restrict__ mu,
              const float* __restrict__ A,
              const float* __restrict__ w,
              float* __restrict__ out) {
    __shared__ __align__(16) float coef[M*8];
    __shared__ float red[256];
    const int t = threadIdx.x;

    float wv[4], c0t[4], c1t[4], c2t[4], c3t[4], c4t[4], c5t[4], dets[4];
    float wmaxl = -3.4e38f;
    #pragma unroll
    for (int k = 0; k < 4; k++) {
        wv[k] = w[t + 256*k];
        wmaxl = fmaxf(wmaxl, wv[k]);
    }
    red[t] = wmaxl; __syncthreads();
    for (int off = 128; off > 0; off >>= 1) {
        if (t < off) red[t] = fmaxf(red[t], red[t+off]);
        __syncthreads();
    }
    const float wmax = red[0]; __syncthreads();
    float se = 0.0f;
    #pragma unroll
    for (int k = 0; k < 4; k++) se += expf(wv[k] - wmax);
    red[t] = se; __syncthreads();
    for (int off = 128; off > 0; off >>= 1) {
        if (t < off) red[t] = red[t] + red[t+off];
        __syncthreads();
    }
    const float lse = wmax + logf(red[0]); __syncthreads();

    float Lml = -3.4e38f;
    float lwk[4];
    #pragma unroll
    for (int k = 0; k < 4; k++) {
        const int j = t + 256*k;
        const float4 a = ((const float4*)A)[j];
        const float g00 = a.x*a.x + a.y*a.y;
        const float g01 = a.x*a.z + a.y*a.w;
        const float g11 = a.z*a.z + a.w*a.w;
        const float2 m  = ((const float2*)mu)[j];
        const float gm0 = g00*m.x + g01*m.y;
        const float gm1 = g01*m.x + g11*m.y;
        const float mGm = gm0*m.x + gm1*m.y;
        dets[k] = g00*g11 - g01*g01;
        lwk[k]  = wv[k] - lse + 0.5f*logf(dets[k]);
        Lml = fmaxf(Lml, lwk[k]);
        c0t[k] = lwk[k] - mGm;
        c1t[k] = 2.0f*gm0;
        c2t[k] = 2.0f*gm1;
        c3t[k] = -g00;
        c4t[k] = -2.0f*g01;
        c5t[k] = -g11;
    }
    red[t] = Lml; __syncthreads();
    for (int off = 128; off > 0; off >>= 1) {
        if (t < off) red[t] = fmaxf(red[t], red[t+off]);
        __syncthreads();
    }
    const float L = red[0];
    #pragma unroll
    for (int k = 0; k < 4; k++) {
        float* c = coef + (t + 256*k)*8;
        c[0] = LOG2E*(c0t[k] - L);
        c[1] = LOG2E*c1t[k];
        c[2] = LOG2E*c2t[k];
        c[3] = LOG2E*c3t[k];
        c[4] = LOG2E*c4t[k];
        c[5] = LOG2E*c5t[k];
    }
    __syncthreads();

    const int i = blockIdx.x*256 + t;
    const float2 xy = ((const float2*)sample)[i];
    const float x0 = xy.x, x1 = xy.y;
    const float xx = x0*x0, xyp = x0*x1, yy = x1*x1;
    float s0 = 0.0f, s1 = 0.0f;
    #pragma unroll 8
    for (int jj = 0; jj < M; jj++) {
        const float* cc = coef + jj*8;
        const float v = fmaf(cc[5], yy,
                        fmaf(cc[4], xyp,
                        fmaf(cc[3], xx,
                        fmaf(cc[2], x1,
                        fmaf(cc[1], x0, cc[0])))));
        const float e = __builtin_amdgcn_exp2f(v);
        if (jj & 1) s1 += e; else s0 += e;
    }
    out[i] = LN2 * (LOG2E*L + __builtin_amdgcn_logf(s0 + s1));
}

extern "C" void kernel_launch(void* const* d_in, const int* in_sizes, int n_in,
                              void* d_out, int out_size, void* d_ws, size_t ws_size,
                              hipStream_t stream) {
    const float* sample = (const float*)d_in[0];
    const float* mu     = (const float*)d_in[1];
    const float* A      = (const float*)d_in[2];
    const float* w      = (const float*)d_in[3];
    float* out = (float*)d_out;

    if (ws_size >= (size_t)(M*8 + 1) * sizeof(float)) {
        gm_prep<<<1, 1024, 0, stream>>>(mu, A, w, (float*)d_ws);
        gm_main<<<N/64, 256, 0, stream>>>(sample, (const float*)d_ws, out);
    } else {
        gm_fused<<<N/256, 256, 0, stream>>>(sample, mu, A, w, out);
    }
}

// Round 2
// 76.321 us; speedup vs baseline: 1.0535x; 1.0535x over previous
//
#include <hip/hip_runtime.h>
#include <math.h>

#define LOG2E 1.4426950408889634f
#define LN2   0.6931471805599453f

static constexpr int M = 1024;
static constexpr int N = 65536;

// ws layout: float coef[M*8] (c0..c5,pad,pad per component, log2e-scaled),
// then float L2 = LOG2E * max_j log_w_j.  Needed ws bytes = (M*8+1)*4.

__device__ inline float wave_max64(float v) {
    #pragma unroll
    for (int o = 32; o > 0; o >>= 1) v = fmaxf(v, __shfl_xor(v, o));
    return v;
}
__device__ inline float wave_sum64(float v) {
    #pragma unroll
    for (int o = 32; o > 0; o >>= 1) v += __shfl_xor(v, o);
    return v;
}

__global__ __launch_bounds__(1024)
void gm_prep(const float* __restrict__ mu,
             const float* __restrict__ A,
             const float* __restrict__ w,
             float* __restrict__ ws) {
    __shared__ float r[16];
    const int j    = threadIdx.x;
    const int lane = j & 63;
    const int wv   = j >> 6;

    // gamma = A A^T (symmetric 2x2)
    const float4 a = ((const float4*)A)[j];          // a00,a01,a10,a11
    const float g00 = a.x*a.x + a.y*a.y;
    const float g01 = a.x*a.z + a.y*a.w;
    const float g11 = a.z*a.z + a.w*a.w;
    const float2 m  = ((const float2*)mu)[j];
    const float gm0 = g00*m.x + g01*m.y;
    const float gm1 = g01*m.x + g11*m.y;
    const float mGm = gm0*m.x + gm1*m.y;
    const float det = g00*g11 - g01*g01;
    const float wj  = w[j];

    // --- block max of w ---
    float t = wave_max64(wj);
    if (lane == 0) r[wv] = t;
    __syncthreads();
    float wmax = r[0];
    #pragma unroll
    for (int i = 1; i < 16; i++) wmax = fmaxf(wmax, r[i]);
    __syncthreads();

    // --- block sum of exp(w - wmax) ---
    t = wave_sum64(expf(wj - wmax));
    if (lane == 0) r[wv] = t;
    __syncthreads();
    float se = 0.0f;
    #pragma unroll
    for (int i = 0; i < 16; i++) se += r[i];
    const float lse = wmax + logf(se);
    __syncthreads();

    const float log_w = wj - lse + 0.5f * logf(det);

    // --- block max of log_w  (global shift L; v = log_w - q <= L) ---
    t = wave_max64(log_w);
    if (lane == 0) r[wv] = t;
    __syncthreads();
    float L = r[0];
    #pragma unroll
    for (int i = 1; i < 16; i++) L = fmaxf(L, r[i]);

    float* c = ws + j*8;
    c[0] = LOG2E * (log_w - mGm - L);
    c[1] = LOG2E * 2.0f * gm0;
    c[2] = LOG2E * 2.0f * gm1;
    c[3] = -LOG2E * g00;
    c[4] = -LOG2E * 2.0f * g01;
    c[5] = -LOG2E * g11;
    c[6] = 0.0f;
    c[7] = 0.0f;
    if (j == 0) ws[M*8] = LOG2E * L;
}

// 256 blocks x 1024 threads. Each block: 256 samples. 16 waves split M
// 16-way (64 components each). Each lane carries S=4 samples so one
// coefficient fetch (2 LDS insts) feeds 20 FMA + 4 exp2 (4 indep chains).
__global__ __launch_bounds__(1024)
void gm_main(const float* __restrict__ sample,
             const float* __restrict__ ws,
             float* __restrict__ out) {
    __shared__ __align__(16) float coef[M*8];     // 32 KiB
    __shared__ float partial[16*256];             // 16 KiB
    const int t = threadIdx.x;

    // stage coefficients global -> LDS (coalesced float4: 2048 float4s)
    const float4* wsv = (const float4*)ws;
    float4* cv = (float4*)coef;
    cv[t]        = wsv[t];
    cv[t + 1024] = wsv[t + 1024];
    __syncthreads();

    const int lane = t & 63;
    const int wave = t >> 6;                       // 0..15
    const int base = blockIdx.x * 256;

    float x0[4], x1[4], xx[4], xy[4], yy[4], acc[4];
    #pragma unroll
    for (int k = 0; k < 4; k++) {
        const float2 p = ((const float2*)sample)[base + 64*k + lane];
        x0[k] = p.x; x1[k] = p.y;
        xx[k] = p.x*p.x; xy[k] = p.x*p.y; yy[k] = p.y*p.y;
        acc[k] = 0.0f;
    }

    const float* c = coef + wave*64*8;
    #pragma unroll 4
    for (int jj = 0; jj < 64; jj++) {
        const float* cc = c + jj*8;
        const float c0 = cc[0], c1 = cc[1], c2 = cc[2];
        const float c3 = cc[3], c4 = cc[4], c5 = cc[5];
        #pragma unroll
        for (int k = 0; k < 4; k++) {
            const float v = fmaf(c5, yy[k],
                            fmaf(c4, xy[k],
                            fmaf(c3, xx[k],
                            fmaf(c2, x1[k],
                            fmaf(c1, x0[k], c0)))));
            acc[k] += __builtin_amdgcn_exp2f(v);
        }
    }

    #pragma unroll
    for (int k = 0; k < 4; k++)
        partial[wave*256 + 64*k + lane] = acc[k];
    __syncthreads();

    if (t < 256) {
        float s = 0.0f;
        #pragma unroll
        for (int w2 = 0; w2 < 16; w2++) s += partial[w2*256 + t];
        out[base + t] = LN2 * (ws[M*8] + __builtin_amdgcn_logf(s));
    }
}

// Fallback if ws is too small (not expected; ws is ~256 MB).
__global__ __launch_bounds__(256)
void gm_fused(const float* __restrict__ sample,
              const float* __restrict__ mu,
              const float* __restrict__ A,
              const float* __restrict__ w,
              float* __restrict__ out) {
    __shared__ __align__(16) float coef[M*8];
    __shared__ float red[256];
    const int t = threadIdx.x;

    float wv[4], c0t[4], c1t[4], c2t[4], c3t[4], c4t[4], c5t[4];
    float wmaxl = -3.4e38f;
    #pragma unroll
    for (int k = 0; k < 4; k++) { wv[k] = w[t + 256*k]; wmaxl = fmaxf(wmaxl, wv[k]); }
    red[t] = wmaxl; __syncthreads();
    for (int off = 128; off > 0; off >>= 1) {
        if (t < off) red[t] = fmaxf(red[t], red[t+off]);
        __syncthreads();
    }
    const float wmax = red[0]; __syncthreads();
    float se = 0.0f;
    #pragma unroll
    for (int k = 0; k < 4; k++) se += expf(wv[k] - wmax);
    red[t] = se; __syncthreads();
    for (int off = 128; off > 0; off >>= 1) {
        if (t < off) red[t] = red[t] + red[t+off];
        __syncthreads();
    }
    const float lse = wmax + logf(red[0]); __syncthreads();

    float Lml = -3.4e38f;
    #pragma unroll
    for (int k = 0; k < 4; k++) {
        const int j = t + 256*k;
        const float4 a = ((const float4*)A)[j];
        const float g00 = a.x*a.x + a.y*a.y;
        const float g01 = a.x*a.z + a.y*a.w;
        const float g11 = a.z*a.z + a.w*a.w;
        const float2 m  = ((const float2*)mu)[j];
        const float gm0 = g00*m.x + g01*m.y;
        const float gm1 = g01*m.x + g11*m.y;
        const float mGm = gm0*m.x + gm1*m.y;
        const float det = g00*g11 - g01*g01;
        const float lw  = wv[k] - lse + 0.5f*logf(det);
        Lml = fmaxf(Lml, lw);
        c0t[k] = lw - mGm; c1t[k] = 2.0f*gm0; c2t[k] = 2.0f*gm1;
        c3t[k] = -g00; c4t[k] = -2.0f*g01; c5t[k] = -g11;
    }
    red[t] = Lml; __syncthreads();
    for (int off = 128; off > 0; off >>= 1) {
        if (t < off) red[t] = fmaxf(red[t], red[t+off]);
        __syncthreads();
    }
    const float L = red[0];
    #pragma unroll
    for (int k = 0; k < 4; k++) {
        float* c = coef + (t + 256*k)*8;
        c[0] = LOG2E*(c0t[k] - L); c[1] = LOG2E*c1t[k]; c[2] = LOG2E*c2t[k];
        c[3] = LOG2E*c3t[k]; c[4] = LOG2E*c4t[k]; c[5] = LOG2E*c5t[k];
    }
    __syncthreads();

    const int i = blockIdx.x*256 + t;
    const float2 xy = ((const float2*)sample)[i];
    const float x0 = xy.x, x1 = xy.y;
    const float xx = x0*x0, xyp = x0*x1, yy = x1*x1;
    float s0 = 0.0f, s1 = 0.0f;
    #pragma unroll 8
    for (int jj = 0; jj < M; jj++) {
        const float* cc = coef + jj*8;
        const float v = fmaf(cc[5], yy,
                        fmaf(cc[4], xyp,
                        fmaf(cc[3], xx,
                        fmaf(cc[2], x1,
                        fmaf(cc[1], x0, cc[0])))));
        const float e = __builtin_amdgcn_exp2f(v);
        if (jj & 1) s1 += e; else s0 += e;
    }
    out[i] = LN2 * (LOG2E*L + __builtin_amdgcn_logf(s0 + s1));
}

extern "C" void kernel_launch(void* const* d_in, const int* in_sizes, int n_in,
                              void* d_out, int out_size, void* d_ws, size_t ws_size,
                              hipStream_t stream) {
    const float* sample = (const float*)d_in[0];
    const float* mu     = (const float*)d_in[1];
    const float* A      = (const float*)d_in[2];
    const float* w      = (const float*)d_in[3];
    float* out = (float*)d_out;

    if (ws_size >= (size_t)(M*8 + 1) * sizeof(float)) {
        gm_prep<<<1, 1024, 0, stream>>>(mu, A, w, (float*)d_ws);
        gm_main<<<N/256, 1024, 0, stream>>>(sample, (const float*)d_ws, out);
    } else {
        gm_fused<<<N/256, 256, 0, stream>>>(sample, mu, A, w, out);
    }
}